// Round 1
// baseline (330.590 us; speedup 1.0000x reference)
//
#include <hip/hip_runtime.h>

// HardBinaryVote: in[31][2000000] int32 in {0,1}; out[b] = (sum_v in[v][b] >= 16)
// 31 voters is odd -> no ties -> majority == (count of ones >= 16).
// Memory-bound: 248 MB read + 8 MB write. Vectorized int4 loads/stores.

constexpr int NV = 31;          // voters
constexpr int BATCH = 2000000;  // batch columns
constexpr int NVEC = BATCH / 4; // int4 elements per row (500000)

__global__ __launch_bounds__(256) void vote_kernel(const int* __restrict__ in,
                                                   int* __restrict__ out) {
    const int vecIdx = blockIdx.x * blockDim.x + threadIdx.x;
    if (vecIdx >= NVEC) return;

    const int4* p = reinterpret_cast<const int4*>(in) + vecIdx;
    int s0 = 0, s1 = 0, s2 = 0, s3 = 0;
#pragma unroll
    for (int v = 0; v < NV; ++v) {
        int4 x = p[(size_t)v * NVEC];   // coalesced: consecutive lanes -> consecutive 16B
        s0 += x.x; s1 += x.y; s2 += x.z; s3 += x.w;
    }
    int4 r;
    r.x = (s0 >= 16) ? 1 : 0;
    r.y = (s1 >= 16) ? 1 : 0;
    r.z = (s2 >= 16) ? 1 : 0;
    r.w = (s3 >= 16) ? 1 : 0;
    reinterpret_cast<int4*>(out)[vecIdx] = r;
}

extern "C" void kernel_launch(void* const* d_in, const int* in_sizes, int n_in,
                              void* d_out, int out_size, void* d_ws, size_t ws_size,
                              hipStream_t stream) {
    const int* in = reinterpret_cast<const int*>(d_in[0]);
    int* out = reinterpret_cast<int*>(d_out);

    const int threads = 256;
    const int blocks = (NVEC + threads - 1) / threads;  // 1954
    vote_kernel<<<blocks, threads, 0, stream>>>(in, out);
}